// Round 2
// baseline (493.984 us; speedup 1.0000x reference)
//
#include <hip/hip_runtime.h>

#define NC 21
#define NB 8
#define HW (512*512)
#define EPS 1e-8f

// Each block: 1024 consecutive pixels of one batch image. Each thread: 4 pixels
// via float4. Argmax over NC channels (strict >, ascending c => first-max
// tie-break, matches jnp.argmax). Scatter target rows into LDS cm tile, then
// flush to per-batch global cm with atomics.
__global__ __launch_bounds__(256) void cm_accum(const float* __restrict__ input,
                                                const float* __restrict__ target,
                                                float* __restrict__ cm /*[NB][NC][NC]*/) {
    __shared__ float scm[NC * NC];
    const int t = threadIdx.x;
    for (int i = t; i < NC * NC; i += 256) scm[i] = 0.0f;
    __syncthreads();

    const int b    = blockIdx.x >> 8;    // 256 tiles per batch
    const int tile = blockIdx.x & 255;
    const int q    = (tile << 8) + t;    // float4 index within a channel plane (HW/4 per plane)

    const float4* ip = (const float4*)(input  + (size_t)b * NC * HW);
    const float4* tp = (const float4*)(target + (size_t)b * NC * HW);
    const int plane4 = HW / 4;

    // argmax over channels, 4 pixels at once
    float4 m = ip[q];
    int jx = 0, jy = 0, jz = 0, jw = 0;
    #pragma unroll
    for (int c = 1; c < NC; ++c) {
        float4 v = ip[c * plane4 + q];
        if (v.x > m.x) { m.x = v.x; jx = c; }
        if (v.y > m.y) { m.y = v.y; jy = c; }
        if (v.z > m.z) { m.z = v.z; jz = c; }
        if (v.w > m.w) { m.w = v.w; jw = c; }
    }

    // scatter target mass into LDS confusion tile
    #pragma unroll
    for (int i = 0; i < NC; ++i) {
        float4 y = tp[i * plane4 + q];
        const int row = i * NC;
        atomicAdd(&scm[row + jx], y.x);
        atomicAdd(&scm[row + jy], y.y);
        atomicAdd(&scm[row + jz], y.z);
        atomicAdd(&scm[row + jw], y.w);
    }
    __syncthreads();

    // flush ALL 441 entries (441 > 256 threads -> strided loop; the round-1
    // bug was `if (t < 441)` which dropped entries 256..440)
    for (int i = t; i < NC * NC; i += 256) atomicAdd(&cm[b * NC * NC + i], scm[i]);
}

// rowsum[b,i] = sum_j cm[b,i,j] (exact identity: one-hot sums to 1 per pixel),
// out[i,j] = mean_b cm[b,i,j] / (rowsum[b,i] + EPS)
__global__ __launch_bounds__(512) void cm_final(const float* __restrict__ cm,
                                                float* __restrict__ out) {
    __shared__ float rs[NB * NC];
    const int t = threadIdx.x;
    if (t < NB * NC) {
        const int b = t / NC, i = t % NC;
        float s = 0.0f;
        for (int j = 0; j < NC; ++j) s += cm[b * NC * NC + i * NC + j];
        rs[t] = s + EPS;
    }
    __syncthreads();
    if (t < NC * NC) {
        const int i = t / NC;
        float acc = 0.0f;
        for (int b = 0; b < NB; ++b) acc += cm[b * NC * NC + t] / rs[b * NC + i];
        out[t] = acc * (1.0f / NB);
    }
}

extern "C" void kernel_launch(void* const* d_in, const int* in_sizes, int n_in,
                              void* d_out, int out_size, void* d_ws, size_t ws_size,
                              hipStream_t stream) {
    const float* input  = (const float*)d_in[0];
    const float* target = (const float*)d_in[1];
    float* out = (float*)d_out;
    float* cm  = (float*)d_ws;   // NB*NC*NC floats

    hipMemsetAsync(cm, 0, NB * NC * NC * sizeof(float), stream);
    cm_accum<<<NB * 256, 256, 0, stream>>>(input, target, cm);
    cm_final<<<1, 512, 0, stream>>>(cm, out);
}